// Round 9
// baseline (570.023 us; speedup 1.0000x reference)
//
#include <hip/hip_runtime.h>

#define N_NODESC 50000
#define N_EDGESC 600000
#define HID 128
#define LAYERS 3
#define N_GRAPHSC 16
#define OUT_DIM 14
#define GEN_EPS 1e-7f
#define BN_EPS 1e-5f
#define SCAN_BLK 196     // ceil(50000/256)
#define POOL_BLK 400     // pool stage-1 blocks (125 rows each)
#define EMB_BLK 6250     // embed blocks (8 rows each)
#define GEMM_BLK 782     // ceil(50000/64)
#define BNR_BLK 64       // bn reduce blocks (coalesced row reads)
#define PLN 50048        // padded rows per channel-chunk plane
#define PLNW (PLN * 8)   // plane stride in uints  (32 B rows)
#define PLNS (PLN * 16)  // plane stride in ushorts
#define NCHUNK 8         // channel chunks (16 ch each): 1.6 MB plane < 4 MB XCD-L2
#define LOG2E 1.44269504f

typedef short bf16x8 __attribute__((ext_vector_type(8)));
typedef float f32x4 __attribute__((ext_vector_type(4)));

__device__ __forceinline__ unsigned short f2bf(float f) {
    union { float f; unsigned u; } v; v.f = f;
    unsigned r = v.u + 0x7FFF + ((v.u >> 16) & 1);  // RNE
    return (unsigned short)(r >> 16);
}
__device__ __forceinline__ float bf_lo(unsigned u) {
    return __uint_as_float(u << 16);
}
__device__ __forceinline__ float bf_hi(unsigned u) {
    return __uint_as_float(u & 0xFFFF0000u);
}

// ---------------- CSR build ----------------
__global__ void k_count(const int* __restrict__ dst, int* __restrict__ deg) {
    int i = blockIdx.x * blockDim.x + threadIdx.x;
    if (i < N_EDGESC) atomicAdd(&deg[dst[i]], 1);
}

__global__ void k_blocksum(const int* __restrict__ deg, int* __restrict__ part) {
    __shared__ int sh[256];
    int t = threadIdx.x;
    int i = blockIdx.x * 256 + t;
    sh[t] = (i < N_NODESC) ? deg[i] : 0;
    __syncthreads();
    for (int off = 128; off > 0; off >>= 1) {
        if (t < off) sh[t] += sh[t + off];
        __syncthreads();
    }
    if (t == 0) part[blockIdx.x] = sh[0];
}

__global__ void k_scanpart(const int* __restrict__ part, int* __restrict__ bofs) {
    __shared__ int sh[256];
    int t = threadIdx.x;
    int v = (t < SCAN_BLK) ? part[t] : 0;
    sh[t] = v;
    __syncthreads();
    for (int off = 1; off < 256; off <<= 1) {
        int add = (t >= off) ? sh[t - off] : 0;
        __syncthreads();
        sh[t] += add;
        __syncthreads();
    }
    if (t < SCAN_BLK) bofs[t] = sh[t] - v;  // exclusive
}

__global__ void k_rowptr(const int* __restrict__ deg, const int* __restrict__ bofs,
                         int* __restrict__ row_ptr, int* __restrict__ cursor) {
    __shared__ int sh[256];
    int t = threadIdx.x;
    int i = blockIdx.x * 256 + t;
    int d = (i < N_NODESC) ? deg[i] : 0;
    sh[t] = d;
    __syncthreads();
    for (int off = 1; off < 256; off <<= 1) {
        int add = (t >= off) ? sh[t - off] : 0;
        __syncthreads();
        sh[t] += add;
        __syncthreads();
    }
    if (i < N_NODESC) {
        int rp = bofs[blockIdx.x] + sh[t] - d;
        row_ptr[i] = rp;
        cursor[i] = rp;
    }
    if (i == 0) row_ptr[N_NODESC] = N_EDGESC;
}

// pack = (src<<8) | f01*8
__global__ void k_scatter(const int* __restrict__ dst, const int* __restrict__ src,
                          const int* __restrict__ f0, const int* __restrict__ f1,
                          int* __restrict__ cursor, int* __restrict__ csr_pack) {
    int i = blockIdx.x * blockDim.x + threadIdx.x;
    if (i < N_EDGESC) {
        int pos = atomicAdd(&cursor[dst[i]], 1);
        csr_pack[pos] = (src[i] << 8) | ((f0[i] * 3 + f1[i]) * 8);
    }
}

// W -> bf16 in MFMA B-fragment order
__global__ void k_wfrag(const float* __restrict__ W, unsigned short* __restrict__ wf) {
    int i = blockIdx.x * blockDim.x + threadIdx.x;
    if (i >= LAYERS * 4 * 8 * 64 * 8) return;
    int j = i & 7;
    int lane = (i >> 3) & 63;
    int nt = (i >> 9) & 7;
    int ks = (i >> 12) & 3;
    int l = i >> 14;
    int k = ks * 32 + (lane >> 4) * 8 + j;
    int n = nt * 16 + (lane & 15);
    wf[i] = f2bf(W[(size_t)l * HID * HID + k * HID + n]);
}

// ---------------- node embedding (+ BN partials for layer 0) ----------------
__global__ void k_embed(const int* __restrict__ f0, const int* __restrict__ f1,
                        const float4* __restrict__ W0, const float4* __restrict__ W1,
                        float4* __restrict__ hv4, float* __restrict__ part) {
    __shared__ float sh[1024], sh2[1024];
    int tid = threadIdx.x;
    int i = blockIdx.x * 256 + tid;
    int v = i >> 5, c4 = i & 31;
    float4 a = W0[f0[v] * 32 + c4];
    float4 b = W1[f1[v] * 32 + c4];
    float4 o = make_float4(a.x + b.x, a.y + b.y, a.z + b.z, a.w + b.w);
    hv4[i] = o;
    sh[tid * 4 + 0] = o.x; sh2[tid * 4 + 0] = o.x * o.x;
    sh[tid * 4 + 1] = o.y; sh2[tid * 4 + 1] = o.y * o.y;
    sh[tid * 4 + 2] = o.z; sh2[tid * 4 + 2] = o.z * o.z;
    sh[tid * 4 + 3] = o.w; sh2[tid * 4 + 3] = o.w * o.w;
    __syncthreads();
    if (tid < 128) {
        int c4i = tid >> 2, j = tid & 3;
        float s = 0.f, s2 = 0.f;
#pragma unroll
        for (int r = 0; r < 8; r++) {
            s += sh[(r * 32 + c4i) * 4 + j];
            s2 += sh2[(r * 32 + c4i) * 4 + j];
        }
        part[(size_t)blockIdx.x * 256 + tid] = s;
        part[(size_t)blockIdx.x * 256 + 128 + tid] = s2;
    }
}

// coalesced partial reduce -> per-layer gsum slots (zeroed once up front)
__global__ void k_bn_reduce2(const float* __restrict__ part, int nparts,
                             float* __restrict__ gsum) {
    int t = threadIdx.x;
    int rows = (nparts + BNR_BLK - 1) / BNR_BLK;
    int r0 = blockIdx.x * rows;
    int r1 = min(r0 + rows, nparts);
    float s = 0.f;
    for (int p = r0; p < r1; p++) s += part[(size_t)p * 256 + t];
    atomicAdd(&gsum[t], s);
}

// BN+ReLU -> bf16 chunk-planes; 4 channels/thread
__global__ void k_hv1b(const float4* __restrict__ hv4, const float* __restrict__ gsum,
                       const float* __restrict__ gamma, const float* __restrict__ betab,
                       unsigned* __restrict__ hv1p) {
    int i = blockIdx.x * 256 + threadIdx.x;   // < 50000*32
    int v = i >> 5, c4 = i & 31;
    int c = c4 * 4;
    const float invN = 1.f / (float)N_NODESC;
    float4 h = hv4[i];
    float r[4];
#pragma unroll
    for (int j = 0; j < 4; j++) {
        float mu = gsum[c + j] * invN;
        float var = gsum[128 + c + j] * invN - mu * mu;
        float sc = gamma[c + j] * rsqrtf(var + BN_EPS);
        float sf = betab[c + j] - mu * sc;
        r[j] = fmaxf(fmaf((&h.x)[j], sc, sf), 0.f);
    }
    uint2 o;
    o.x = (unsigned)f2bf(r[0]) | ((unsigned)f2bf(r[1]) << 16);
    o.y = (unsigned)f2bf(r[2]) | ((unsigned)f2bf(r[3]) << 16);
    int ck = c4 >> 2;
    *(uint2*)(hv1p + (size_t)ck * PLNW + (size_t)v * 8 + (c4 & 3) * 2) = o;
}

// ---------------- GENConv aggregation: XCD channel-sharded ------------------
// chunk ck = blockIdx&7 (pins to one XCD under round-robin dispatch); plane =
// 1.6 MB -> L2-resident with full deg-12 reuse. One octet (8 lanes) per node,
// 2 channels/lane; loop to wave-max degree with lane masking.
__global__ __launch_bounds__(512) void k_agg(
    const unsigned* __restrict__ hv1p, const int* __restrict__ row_ptr,
    const int* __restrict__ csr_pack, const float* __restrict__ e0,
    const float* __restrict__ e1, const float* __restrict__ beta_p,
    unsigned* __restrict__ xbp) {
    __shared__ float2 sh_et[18 * 8];   // [f01][s]; row = 64 B
    int tid = threadIdx.x;
    int ck = blockIdx.x & 7;
    int ng = blockIdx.x >> 3;
    if (tid < 144) {
        int f = tid >> 3, sl = tid & 7;
        int a = f / 3, b = f - 3 * a;
        int c0 = ck * 16 + sl * 2;
        float2 ea = *(const float2*)(e0 + a * HID + c0);
        float2 eb = *(const float2*)(e1 + b * HID + c0);
        sh_et[tid] = make_float2(ea.x + eb.x, ea.y + eb.y);
    }
    int wave = tid >> 6, lane = tid & 63;
    int oct = lane >> 3, s = lane & 7;
    int v = ng * 64 + wave * 8 + oct;     // < 50048
    float beta = *beta_p;
    const float bl2 = beta * LOG2E;
    __syncthreads();
    const unsigned* plane = hv1p + (size_t)ck * PLNW;
    unsigned su = plane[v * 8 + s];
    int vc = min(v, N_NODESC);
    int p0 = row_ptr[vc];
    int deg = row_ptr[min(vc + 1, N_NODESC)] - p0;
    // wave-uniform max degree (octets differ only in lane bits 3..5)
    int dd = deg;
    dd = max(dd, __shfl_xor(dd, 8, 64));
    dd = max(dd, __shfl_xor(dd, 16, 64));
    dd = max(dd, __shfl_xor(dd, 32, 64));
    int dmax = __builtin_amdgcn_readfirstlane(dd);
    float n0 = 0.f, n1 = 0.f, d0 = 0.f, d1 = 0.f;
    const char* pc = (const char*)plane;
    const char* etc = (const char*)sh_et;
    unsigned s4 = (unsigned)s * 4, s8 = (unsigned)s * 8;
    int dm1 = deg - 1;
#pragma unroll 2
    for (int j = 0; j < dmax; j++) {
        bool on = j < deg;
        int pidx = min(p0 + max(0, min(j, dm1)), N_EDGESC - 1);  // clamped safe
        int pk = __builtin_nontemporal_load(&csr_pack[pidx]);
        unsigned u = *(const unsigned*)(pc +
                        ((((unsigned)pk & 0xFFFFFF00u) >> 3) | s4));
        float2 t = *(const float2*)(etc +
                        ((((unsigned)pk & 0xFFu) << 3) | s8));
        float r0 = fmaxf(bf_lo(u) + t.x, 0.f);
        float r1 = fmaxf(bf_hi(u) + t.y, 0.f);
        float w0 = exp2f(r0 * bl2), w1 = exp2f(r1 * bl2);
        w0 = on ? w0 : 0.f;
        w1 = on ? w1 : 0.f;
        d0 += w0; d1 += w1;
        n0 = fmaf(r0, w0, n0); n1 = fmaf(r1, w1, n1);
    }
    float o0 = bf_lo(su) + (deg ? __fdividef(n0, d0) + GEN_EPS : 0.f);
    float o1 = bf_hi(su) + (deg ? __fdividef(n1, d1) + GEN_EPS : 0.f);
    if (v < N_NODESC)
        xbp[(size_t)ck * PLNW + (size_t)v * 8 + s] =
            (unsigned)f2bf(o0) | ((unsigned)f2bf(o1) << 16);
}

// ---------------- MFMA GEMM + bias + skip + next-layer BN partials ----------
// x now in chunk-planes: af[ks] channels ks*32+grp*8.. map to chunk ks*2+grp/2
__global__ __launch_bounds__(256) void k_gemm(
    const unsigned short* __restrict__ x,   // 8 planes [PLN][16ch] bf16
    const unsigned short* __restrict__ wf,  // [4][8][64][8] bf16 frags
    const float* __restrict__ b, float* __restrict__ hv,
    float* __restrict__ part) {
    __shared__ float shs[512], shs2[512];
    int tid = threadIdx.x;
    int w = tid >> 6, lane = tid & 63;
    int m0 = blockIdx.x * 64 + w * 16;
    int mrow = lane & 15, grp = lane >> 4;
    bf16x8 af[4];
#pragma unroll
    for (int ks = 0; ks < 4; ks++) {
        int ckp = ks * 2 + (grp >> 1);
        af[ks] = *(const bf16x8*)(x + (size_t)ckp * PLNS +
                                  (size_t)(m0 + mrow) * 16 + (grp & 1) * 8);
    }
    f32x4 acc[8];
#pragma unroll
    for (int nt = 0; nt < 8; nt++) acc[nt] = (f32x4){0.f, 0.f, 0.f, 0.f};
#pragma unroll
    for (int nt = 0; nt < 8; nt++) {
#pragma unroll
        for (int ks = 0; ks < 4; ks++) {
            bf16x8 bf = *(const bf16x8*)(wf + (size_t)((ks * 8 + nt) * 64 + lane) * 8);
            acc[nt] = __builtin_amdgcn_mfma_f32_16x16x32_bf16(af[ks], bf, acc[nt], 0, 0, 0);
        }
    }
#pragma unroll
    for (int nt = 0; nt < 8; nt++) {
        int col = nt * 16 + mrow;
        float bias = b[col];
        float s = 0.f, s2 = 0.f;
#pragma unroll
        for (int r = 0; r < 4; r++) {
            int v = m0 + grp * 4 + r;
            if (v < N_NODESC) {
                size_t idx = (size_t)v * HID + col;
                float o = acc[nt][r] + bias + hv[idx];
                hv[idx] = o;
                s += o; s2 += o * o;
            }
        }
        s  += __shfl_xor(s, 16, 64);  s  += __shfl_xor(s, 32, 64);
        s2 += __shfl_xor(s2, 16, 64); s2 += __shfl_xor(s2, 32, 64);
        if (lane < 16) { shs[w * 128 + col] = s; shs2[w * 128 + col] = s2; }
    }
    __syncthreads();
    if (tid < 128) {
        part[(size_t)blockIdx.x * 256 + tid] =
            shs[tid] + shs[128 + tid] + shs[256 + tid] + shs[384 + tid];
    } else {
        int c = tid - 128;
        part[(size_t)blockIdx.x * 256 + tid] =
            shs2[c] + shs2[128 + c] + shs2[256 + c] + shs2[384 + c];
    }
}

// ---------------- pooling stage 1 ----------------
__global__ void k_pool(const float* __restrict__ hv, float* __restrict__ part2) {
    int tid = threadIdx.x;
    int c = tid & 127, rh = tid >> 7;
    int start = blockIdx.x * 125;
    float acc = 0.f;
    for (int r = start + rh; r < start + 125; r += 2)
        acc += hv[(size_t)r * HID + c];
    __shared__ float sh[256];
    sh[tid] = acc;
    __syncthreads();
    if (rh == 0) part2[blockIdx.x * 128 + c] = acc + sh[tid + 128];
}

// ---------------- pooling stage 2 + output linear (one block) ----------------
__global__ void k_finish(const float* __restrict__ part2, const float* __restrict__ Wo,
                         const float* __restrict__ bo, float* __restrict__ out) {
    __shared__ float hg[N_GRAPHSC * HID];
    int t = threadIdx.x;
    for (int s = t; s < N_GRAPHSC * HID; s += 256) {
        int g = s >> 7, c = s & 127;
        float x = 0.f;
#pragma unroll
        for (int i = 0; i < 25; i++) x += part2[(g * 25 + i) * 128 + c];
        hg[s] = x;
    }
    __syncthreads();
    if (t < N_GRAPHSC * OUT_DIM) {
        int g = t / OUT_DIM, o = t % OUT_DIM;
        const float inv = (float)N_GRAPHSC / (float)N_NODESC;
        float acc = bo[o];
        for (int k = 0; k < HID; k++)
            acc += hg[g * HID + k] * inv * Wo[k * OUT_DIM + o];
        out[t] = acc;
    }
}

extern "C" void kernel_launch(void* const* d_in, const int* in_sizes, int n_in,
                              void* d_out, int out_size, void* d_ws, size_t ws_size,
                              hipStream_t stream) {
    const int* node_feat0 = (const int*)d_in[0];
    const int* node_feat1 = (const int*)d_in[1];
    const int* edge_feat0 = (const int*)d_in[2];
    const int* edge_feat1 = (const int*)d_in[3];
    const int* edge_src   = (const int*)d_in[4];
    const int* edge_dst   = (const int*)d_in[5];
    const float* W_node0   = (const float*)d_in[8];
    const float* W_node1   = (const float*)d_in[9];
    const float* edge_emb0 = (const float*)d_in[10];
    const float* edge_emb1 = (const float*)d_in[11];
    const float* beta      = (const float*)d_in[12];
    const float* mlp_W     = (const float*)d_in[13];
    const float* mlp_b     = (const float*)d_in[14];
    const float* bn_gamma  = (const float*)d_in[15];
    const float* bn_beta   = (const float*)d_in[16];
    const float* W_out     = (const float*)d_in[17];
    const float* b_out     = (const float*)d_in[18];
    float* out = (float*)d_out;

    char* ws = (char*)d_ws;
    size_t off = 0;
    auto alloc = [&](size_t bytes) -> void* {
        void* p = ws + off;
        off += (bytes + 255) & ~(size_t)255;
        return p;
    };
    float* hv      = (float*)alloc((size_t)N_NODESC * HID * 4);
    unsigned* xbp  = (unsigned*)alloc((size_t)NCHUNK * PLNW * 4);   // x planes
    unsigned* hv1p = (unsigned*)alloc((size_t)NCHUNK * PLNW * 4);   // hv1 planes
    float* bnpart  = (float*)alloc((size_t)EMB_BLK * 256 * 4);
    float* gsums   = (float*)alloc(LAYERS * 256 * 4);
    unsigned short* wfrag = (unsigned short*)alloc((size_t)LAYERS * 16384 * 2);
    float* part2   = (float*)alloc(POOL_BLK * 128 * 4);
    int* row_ptr   = (int*)alloc((N_NODESC + 1) * 4);
    int* cursor    = (int*)alloc(N_NODESC * 4);
    int* deg       = (int*)alloc(N_NODESC * 4);
    int* part      = (int*)alloc(SCAN_BLK * 4);
    int* bofs      = (int*)alloc(SCAN_BLK * 4);
    int* csr_pack  = (int*)alloc((size_t)N_EDGESC * 4);

    // ---- CSR build (edge_dst is layer-invariant) ----
    hipMemsetAsync(deg, 0, N_NODESC * 4, stream);
    hipMemsetAsync(gsums, 0, LAYERS * 256 * 4, stream);
    k_count<<<(N_EDGESC + 255) / 256, 256, 0, stream>>>(edge_dst, deg);
    k_blocksum<<<SCAN_BLK, 256, 0, stream>>>(deg, part);
    k_scanpart<<<1, 256, 0, stream>>>(part, bofs);
    k_rowptr<<<SCAN_BLK, 256, 0, stream>>>(deg, bofs, row_ptr, cursor);
    k_scatter<<<(N_EDGESC + 255) / 256, 256, 0, stream>>>(
        edge_dst, edge_src, edge_feat0, edge_feat1, cursor, csr_pack);
    k_wfrag<<<(LAYERS * 16384 + 255) / 256, 256, 0, stream>>>(mlp_W, wfrag);

    // ---- node embedding (+ layer-0 BN partials) ----
    k_embed<<<EMB_BLK, 256, 0, stream>>>(
        node_feat0, node_feat1, (const float4*)W_node0, (const float4*)W_node1,
        (float4*)hv, bnpart);

    // ---- layers ----
    for (int l = 0; l < LAYERS; l++) {
        float* gsum = gsums + l * 256;
        int nparts = (l == 0) ? EMB_BLK : GEMM_BLK;
        k_bn_reduce2<<<BNR_BLK, 256, 0, stream>>>(bnpart, nparts, gsum);
        k_hv1b<<<(N_NODESC * 32) / 256, 256, 0, stream>>>(
            (const float4*)hv, gsum, bn_gamma + l * HID, bn_beta + l * HID, hv1p);
        k_agg<<<GEMM_BLK * NCHUNK, 512, 0, stream>>>(
            hv1p, row_ptr, csr_pack,
            edge_emb0 + (size_t)l * 6 * HID, edge_emb1 + (size_t)l * 3 * HID,
            beta + l, xbp);
        k_gemm<<<GEMM_BLK, 256, 0, stream>>>(
            (const unsigned short*)xbp, wfrag + (size_t)l * 16384,
            mlp_b + l * HID, hv, bnpart);
    }

    // ---- pooling + output ----
    k_pool<<<POOL_BLK, 256, 0, stream>>>(hv, part2);
    k_finish<<<1, 256, 0, stream>>>(part2, W_out, b_out, out);
}

// Round 10
// 454.198 us; speedup vs baseline: 1.2550x; 1.2550x over previous
//
#include <hip/hip_runtime.h>

#define N_NODESC 50000
#define N_EDGESC 600000
#define HID 128
#define LAYERS 3
#define N_GRAPHSC 16
#define OUT_DIM 14
#define GEN_EPS 1e-7f
#define BN_EPS 1e-5f
#define SCAN_BLK 196     // ceil(50000/256)
#define POOL_BLK 400     // pool stage-1 blocks (125 rows each)
#define EMB_BLK 6250     // embed blocks (8 rows each)
#define WF_BLK 192       // wfrag blocks appended to embed grid
#define GEMM_BLK 782     // ceil(50000/64)
#define BNR_BLK 64       // bn reduce blocks (coalesced row reads)
#define LOG2E 1.44269504f

typedef short bf16x8 __attribute__((ext_vector_type(8)));
typedef float f32x4 __attribute__((ext_vector_type(4)));

__device__ __forceinline__ unsigned short f2bf(float f) {
    union { float f; unsigned u; } v; v.f = f;
    unsigned r = v.u + 0x7FFF + ((v.u >> 16) & 1);  // RNE
    return (unsigned short)(r >> 16);
}
__device__ __forceinline__ float bf_lo(unsigned u) {
    return __uint_as_float(u << 16);
}
__device__ __forceinline__ float bf_hi(unsigned u) {
    return __uint_as_float(u & 0xFFFF0000u);
}

// ---------------- CSR build ----------------
__global__ void k_count(const int* __restrict__ dst, int* __restrict__ deg) {
    int i = blockIdx.x * blockDim.x + threadIdx.x;
    if (i < N_EDGESC) atomicAdd(&deg[dst[i]], 1);
}

__global__ void k_blocksum(const int* __restrict__ deg, int* __restrict__ part) {
    __shared__ int sh[256];
    int t = threadIdx.x;
    int i = blockIdx.x * 256 + t;
    sh[t] = (i < N_NODESC) ? deg[i] : 0;
    __syncthreads();
    for (int off = 128; off > 0; off >>= 1) {
        if (t < off) sh[t] += sh[t + off];
        __syncthreads();
    }
    if (t == 0) part[blockIdx.x] = sh[0];
}

__global__ void k_scanpart(const int* __restrict__ part, int* __restrict__ bofs) {
    __shared__ int sh[256];
    int t = threadIdx.x;
    int v = (t < SCAN_BLK) ? part[t] : 0;
    sh[t] = v;
    __syncthreads();
    for (int off = 1; off < 256; off <<= 1) {
        int add = (t >= off) ? sh[t - off] : 0;
        __syncthreads();
        sh[t] += add;
        __syncthreads();
    }
    if (t < SCAN_BLK) bofs[t] = sh[t] - v;  // exclusive
}

__global__ void k_rowptr(const int* __restrict__ deg, const int* __restrict__ bofs,
                         int* __restrict__ row_ptr, int* __restrict__ cursor) {
    __shared__ int sh[256];
    int t = threadIdx.x;
    int i = blockIdx.x * 256 + t;
    int d = (i < N_NODESC) ? deg[i] : 0;
    sh[t] = d;
    __syncthreads();
    for (int off = 1; off < 256; off <<= 1) {
        int add = (t >= off) ? sh[t - off] : 0;
        __syncthreads();
        sh[t] += add;
        __syncthreads();
    }
    if (i < N_NODESC) {
        int rp = bofs[blockIdx.x] + sh[t] - d;
        row_ptr[i] = rp;
        cursor[i] = rp;
    }
    if (i == 0) row_ptr[N_NODESC] = N_EDGESC;
}

// pack = (src<<8) | f01*8 : & 0xFFFFFF00 = byte row offset (256 B rows),
//                           (& 0xFF)<<6  = f01*512 byte offset into etab
__global__ void k_scatter(const int* __restrict__ dst, const int* __restrict__ src,
                          const int* __restrict__ f0, const int* __restrict__ f1,
                          int* __restrict__ cursor, int* __restrict__ csr_pack) {
    int i = blockIdx.x * blockDim.x + threadIdx.x;
    if (i < N_EDGESC) {
        int pos = atomicAdd(&cursor[dst[i]], 1);
        csr_pack[pos] = (src[i] << 8) | ((f0[i] * 3 + f1[i]) * 8);
    }
}

// ---------------- node embedding (+ BN partials) + wfrag tail ----------------
__global__ void k_embed(const int* __restrict__ f0, const int* __restrict__ f1,
                        const float4* __restrict__ W0, const float4* __restrict__ W1,
                        float4* __restrict__ hv4, float* __restrict__ part,
                        const float* __restrict__ W, unsigned short* __restrict__ wf) {
    int tid = threadIdx.x;
    if (blockIdx.x >= EMB_BLK) {
        // W -> bf16 in MFMA B-fragment order
        int i = (blockIdx.x - EMB_BLK) * 256 + tid;
        if (i < LAYERS * 4 * 8 * 64 * 8) {
            int j = i & 7;
            int lane = (i >> 3) & 63;
            int nt = (i >> 9) & 7;
            int ks = (i >> 12) & 3;
            int l = i >> 14;
            int k = ks * 32 + (lane >> 4) * 8 + j;
            int n = nt * 16 + (lane & 15);
            wf[i] = f2bf(W[(size_t)l * HID * HID + k * HID + n]);
        }
        return;
    }
    __shared__ float sh[1024], sh2[1024];
    int i = blockIdx.x * 256 + tid;
    int v = i >> 5, c4 = i & 31;
    float4 a = W0[f0[v] * 32 + c4];
    float4 b = W1[f1[v] * 32 + c4];
    float4 o = make_float4(a.x + b.x, a.y + b.y, a.z + b.z, a.w + b.w);
    hv4[i] = o;
    sh[tid * 4 + 0] = o.x; sh2[tid * 4 + 0] = o.x * o.x;
    sh[tid * 4 + 1] = o.y; sh2[tid * 4 + 1] = o.y * o.y;
    sh[tid * 4 + 2] = o.z; sh2[tid * 4 + 2] = o.z * o.z;
    sh[tid * 4 + 3] = o.w; sh2[tid * 4 + 3] = o.w * o.w;
    __syncthreads();
    if (tid < 128) {
        int c4i = tid >> 2, j = tid & 3;
        float s = 0.f, s2 = 0.f;
#pragma unroll
        for (int r = 0; r < 8; r++) {
            s += sh[(r * 32 + c4i) * 4 + j];
            s2 += sh2[(r * 32 + c4i) * 4 + j];
        }
        part[(size_t)blockIdx.x * 256 + tid] = s;
        part[(size_t)blockIdx.x * 256 + 128 + tid] = s2;
    }
}

// coalesced partial reduce -> per-layer gsum slots (zeroed once up front)
__global__ void k_bn_reduce2(const float* __restrict__ part, int nparts,
                             float* __restrict__ gsum) {
    int t = threadIdx.x;
    int rows = (nparts + BNR_BLK - 1) / BNR_BLK;
    int r0 = blockIdx.x * rows;
    int r1 = min(r0 + rows, nparts);
    float s = 0.f;
    for (int p = r0; p < r1; p++) s += part[(size_t)p * 256 + t];
    atomicAdd(&gsum[t], s);
}

// BN+ReLU -> bf16 pair-packed hv1 (row-major, 256 B rows); 4 channels/thread
__global__ void k_hv1b(const float4* __restrict__ hv4, const float* __restrict__ gsum,
                       const float* __restrict__ gamma, const float* __restrict__ betab,
                       uint2* __restrict__ hv1b) {
    int i = blockIdx.x * 256 + threadIdx.x;   // < 50000*32
    int c = (i & 31) * 4;
    const float invN = 1.f / (float)N_NODESC;
    float4 h = hv4[i];
    float r[4];
#pragma unroll
    for (int j = 0; j < 4; j++) {
        float mu = gsum[c + j] * invN;
        float var = gsum[128 + c + j] * invN - mu * mu;
        float sc = gamma[c + j] * rsqrtf(var + BN_EPS);
        float sf = betab[c + j] - mu * sc;
        r[j] = fmaxf(fmaf((&h.x)[j], sc, sf), 0.f);
    }
    uint2 o;
    o.x = (unsigned)f2bf(r[0]) | ((unsigned)f2bf(r[1]) << 16);
    o.y = (unsigned)f2bf(r[2]) | ((unsigned)f2bf(r[3]) << 16);
    hv1b[i] = o;
}

// ---------------- FUSED: GENConv aggregation -> LDS -> MFMA GEMM ------------
// Block = 64 nodes, 512 threads (8 waves).
// Phase 1 (agg): wave w computes nodes m0+w*8..+7 (R8 structure), writes bf16
//   rows to LDS x_tile with rotated cols (conflict-free write AND b128 read).
// Phase 2 (MFMA): wave w -> rows (w&3)*16.., cols (w>>2)*64.. ; epilogue does
//   bias + fp32 skip into hv + next-layer BN partials.
__global__ __launch_bounds__(512) void k_aggemm(
    const unsigned* __restrict__ hv1b, const int* __restrict__ row_ptr,
    const int* __restrict__ csr_pack, const float* __restrict__ e0,
    const float* __restrict__ e1, const float* __restrict__ beta_p,
    const unsigned short* __restrict__ wf, const float* __restrict__ b,
    float* __restrict__ hv, float* __restrict__ part) {
    __shared__ float2 sh_et[18 * 64];      // 9216 B: [f01][lane] ch (2l,2l+1)
    __shared__ unsigned x_tile[64 * 64];   // 16384 B: [row][rot col]
    __shared__ float shs[512], shs2[512];  // 4096 B
    int tid = threadIdx.x;
    for (int i = tid; i < 18 * 64; i += 512) {
        int f = i >> 6, ln = i & 63;
        int a = f / 3, bb = f - 3 * a;
        float2 ea = *(const float2*)(e0 + a * HID + 2 * ln);
        float2 eb = *(const float2*)(e1 + bb * HID + 2 * ln);
        sh_et[i] = make_float2(ea.x + eb.x, ea.y + eb.y);
    }
    int w = tid >> 6, lane = tid & 63;
    int m0 = blockIdx.x * 64;
    float beta = *beta_p;
    const float bl2 = beta * LOG2E;
    __syncthreads();

    const char* hv1c = (const char*)hv1b;
    const char* etc = (const char*)sh_et;
    unsigned lane4 = (unsigned)lane * 4;
    unsigned lane8 = (unsigned)lane * 8;

#define AGG_BODY(J)                                                         \
    {                                                                       \
        int pack = __shfl(pk, (J), 64);                                     \
        unsigned u = *(const unsigned*)(hv1c +                              \
                        ((((unsigned)pack) & 0xFFFFFF00u) + lane4));        \
        float2 t = *(const float2*)(etc +                                   \
                        (((((unsigned)pack) & 0xFFu) << 6) + lane8));       \
        float r0 = fmaxf(bf_lo(u) + t.x, 0.f);                              \
        float r1 = fmaxf(bf_hi(u) + t.y, 0.f);                              \
        float w0 = exp2f(r0 * bl2);                                         \
        float w1 = exp2f(r1 * bl2);                                         \
        d0 += w0; d1 += w1;                                                 \
        n0 = fmaf(r0, w0, n0); n1 = fmaf(r1, w1, n1);                       \
    }

    // ---- phase 1: aggregation, 8 nodes per wave ----
    for (int i = 0; i < 8; i++) {
        int row = w * 8 + i;
        int v = m0 + row;
        int vc = min(v, N_NODESC - 1);
        unsigned su = hv1b[(size_t)vc * 64 + lane];
        int p0 = row_ptr[vc];
        int deg = (v < N_NODESC) ? (row_ptr[vc + 1] - p0) : 0;
        float n0 = 0.f, n1 = 0.f, d0 = 0.f, d1 = 0.f;
        for (int base = 0; base < deg; base += 64) {
            int idx = base + lane;
            int pk = (idx < deg) ? csr_pack[p0 + idx] : 0;
            int jn = min(64, deg - base);
            int j = 0;
            for (; j + 2 <= jn; j += 2) {
                AGG_BODY(j)
                AGG_BODY(j + 1)
            }
            if (j < jn) AGG_BODY(j)
        }
        float ox = bf_lo(su) + (deg ? __fdividef(n0, d0) + GEN_EPS : 0.f);
        float oy = bf_hi(su) + (deg ? __fdividef(n1, d1) + GEN_EPS : 0.f);
        // rotated col: (lane + row*4) & 63 — stride-4 rotate keeps b128 frags
        // contiguous and spreads banks in both phases
        x_tile[row * 64 + ((lane + row * 4) & 63)] =
            (unsigned)f2bf(ox) | ((unsigned)f2bf(oy) << 16);
    }
#undef AGG_BODY
    __syncthreads();

    // ---- phase 2: MFMA ----
    int rw = w & 3, chh = w >> 2;          // row-wave, col-half
    int mrow = lane & 15, grp = lane >> 4;
    int rbase = rw * 16 + mrow;
    bf16x8 af[4];
#pragma unroll
    for (int ks = 0; ks < 4; ks++) {
        int col = ks * 16 + grp * 4;                 // uint col of fragment
        int colr = (col + rbase * 4) & 63;           // rotated
        af[ks] = *(const bf16x8*)&x_tile[rbase * 64 + colr];
    }
    f32x4 acc[4];
#pragma unroll
    for (int nt = 0; nt < 4; nt++) acc[nt] = (f32x4){0.f, 0.f, 0.f, 0.f};
#pragma unroll
    for (int nt = 0; nt < 4; nt++) {
        int ntg = chh * 4 + nt;
#pragma unroll
        for (int ks = 0; ks < 4; ks++) {
            bf16x8 bfr = *(const bf16x8*)(wf + (size_t)((ks * 8 + ntg) * 64 + lane) * 8);
            acc[nt] = __builtin_amdgcn_mfma_f32_16x16x32_bf16(af[ks], bfr, acc[nt], 0, 0, 0);
        }
    }
    // epilogue: bias + skip + store + per-column partial stats
#pragma unroll
    for (int nt = 0; nt < 4; nt++) {
        int col = chh * 64 + nt * 16 + mrow;
        float bias = b[col];
        float s = 0.f, s2 = 0.f;
#pragma unroll
        for (int r = 0; r < 4; r++) {
            int v = m0 + rw * 16 + grp * 4 + r;
            if (v < N_NODESC) {
                size_t idx = (size_t)v * HID + col;
                float o = acc[nt][r] + bias + hv[idx];
                hv[idx] = o;
                s += o; s2 += o * o;
            }
        }
        s  += __shfl_xor(s, 16, 64);  s  += __shfl_xor(s, 32, 64);
        s2 += __shfl_xor(s2, 16, 64); s2 += __shfl_xor(s2, 32, 64);
        if (lane < 16) { shs[rw * 128 + col] = s; shs2[rw * 128 + col] = s2; }
    }
    __syncthreads();
    if (tid < 128) {
        part[(size_t)blockIdx.x * 256 + tid] =
            shs[tid] + shs[128 + tid] + shs[256 + tid] + shs[384 + tid];
    } else if (tid < 256) {
        int c = tid - 128;
        part[(size_t)blockIdx.x * 256 + tid] =
            shs2[c] + shs2[128 + c] + shs2[256 + c] + shs2[384 + c];
    }
}

// ---------------- pooling stage 1 ----------------
__global__ void k_pool(const float* __restrict__ hv, float* __restrict__ part2) {
    int tid = threadIdx.x;
    int c = tid & 127, rh = tid >> 7;
    int start = blockIdx.x * 125;
    float acc = 0.f;
    for (int r = start + rh; r < start + 125; r += 2)
        acc += hv[(size_t)r * HID + c];
    __shared__ float sh[256];
    sh[tid] = acc;
    __syncthreads();
    if (rh == 0) part2[blockIdx.x * 128 + c] = acc + sh[tid + 128];
}

// ---------------- pooling stage 2 + output linear (one block) ----------------
__global__ void k_finish(const float* __restrict__ part2, const float* __restrict__ Wo,
                         const float* __restrict__ bo, float* __restrict__ out) {
    __shared__ float hg[N_GRAPHSC * HID];
    int t = threadIdx.x;
    for (int s = t; s < N_GRAPHSC * HID; s += 256) {
        int g = s >> 7, c = s & 127;
        float x = 0.f;
#pragma unroll
        for (int i = 0; i < 25; i++) x += part2[(g * 25 + i) * 128 + c];
        hg[s] = x;
    }
    __syncthreads();
    if (t < N_GRAPHSC * OUT_DIM) {
        int g = t / OUT_DIM, o = t % OUT_DIM;
        const float inv = (float)N_GRAPHSC / (float)N_NODESC;
        float acc = bo[o];
        for (int k = 0; k < HID; k++)
            acc += hg[g * HID + k] * inv * Wo[k * OUT_DIM + o];
        out[t] = acc;
    }
}

extern "C" void kernel_launch(void* const* d_in, const int* in_sizes, int n_in,
                              void* d_out, int out_size, void* d_ws, size_t ws_size,
                              hipStream_t stream) {
    const int* node_feat0 = (const int*)d_in[0];
    const int* node_feat1 = (const int*)d_in[1];
    const int* edge_feat0 = (const int*)d_in[2];
    const int* edge_feat1 = (const int*)d_in[3];
    const int* edge_src   = (const int*)d_in[4];
    const int* edge_dst   = (const int*)d_in[5];
    const float* W_node0   = (const float*)d_in[8];
    const float* W_node1   = (const float*)d_in[9];
    const float* edge_emb0 = (const float*)d_in[10];
    const float* edge_emb1 = (const float*)d_in[11];
    const float* beta      = (const float*)d_in[12];
    const float* mlp_W     = (const float*)d_in[13];
    const float* mlp_b     = (const float*)d_in[14];
    const float* bn_gamma  = (const float*)d_in[15];
    const float* bn_beta   = (const float*)d_in[16];
    const float* W_out     = (const float*)d_in[17];
    const float* b_out     = (const float*)d_in[18];
    float* out = (float*)d_out;

    char* ws = (char*)d_ws;
    size_t off = 0;
    auto alloc = [&](size_t bytes) -> void* {
        void* p = ws + off;
        off += (bytes + 255) & ~(size_t)255;
        return p;
    };
    float* hv      = (float*)alloc((size_t)N_NODESC * HID * 4);
    unsigned* hv1b = (unsigned*)alloc((size_t)N_NODESC * 64 * 4);  // bf16 pairs
    float* bnpart  = (float*)alloc((size_t)EMB_BLK * 256 * 4);
    float* gsums   = (float*)alloc(LAYERS * 256 * 4);
    unsigned short* wfrag = (unsigned short*)alloc((size_t)LAYERS * 16384 * 2);
    float* part2   = (float*)alloc(POOL_BLK * 128 * 4);
    int* row_ptr   = (int*)alloc((N_NODESC + 1) * 4);
    int* cursor    = (int*)alloc(N_NODESC * 4);
    int* deg       = (int*)alloc(N_NODESC * 4);
    int* part      = (int*)alloc(SCAN_BLK * 4);
    int* bofs      = (int*)alloc(SCAN_BLK * 4);
    int* csr_pack  = (int*)alloc((size_t)N_EDGESC * 4);

    // ---- CSR build (edge_dst is layer-invariant) ----
    hipMemsetAsync(deg, 0, N_NODESC * 4, stream);
    hipMemsetAsync(gsums, 0, LAYERS * 256 * 4, stream);
    k_count<<<(N_EDGESC + 255) / 256, 256, 0, stream>>>(edge_dst, deg);
    k_blocksum<<<SCAN_BLK, 256, 0, stream>>>(deg, part);
    k_scanpart<<<1, 256, 0, stream>>>(part, bofs);
    k_rowptr<<<SCAN_BLK, 256, 0, stream>>>(deg, bofs, row_ptr, cursor);
    k_scatter<<<(N_EDGESC + 255) / 256, 256, 0, stream>>>(
        edge_dst, edge_src, edge_feat0, edge_feat1, cursor, csr_pack);

    // ---- node embedding (+ layer-0 BN partials) + wfrag tail ----
    k_embed<<<EMB_BLK + WF_BLK, 256, 0, stream>>>(
        node_feat0, node_feat1, (const float4*)W_node0, (const float4*)W_node1,
        (float4*)hv, bnpart, mlp_W, wfrag);

    // ---- layers ----
    for (int l = 0; l < LAYERS; l++) {
        float* gsum = gsums + l * 256;
        int nparts = (l == 0) ? EMB_BLK : GEMM_BLK;
        k_bn_reduce2<<<BNR_BLK, 256, 0, stream>>>(bnpart, nparts, gsum);
        k_hv1b<<<(N_NODESC * 32) / 256, 256, 0, stream>>>(
            (const float4*)hv, gsum, bn_gamma + l * HID, bn_beta + l * HID,
            (uint2*)hv1b);
        k_aggemm<<<GEMM_BLK, 512, 0, stream>>>(
            hv1b, row_ptr, csr_pack,
            edge_emb0 + (size_t)l * 6 * HID, edge_emb1 + (size_t)l * 3 * HID,
            beta + l, wfrag + (size_t)l * 16384, mlp_b + l * HID, hv, bnpart);
    }

    // ---- pooling + output ----
    k_pool<<<POOL_BLK, 256, 0, stream>>>(hv, part2);
    k_finish<<<1, 256, 0, stream>>>(part2, W_out, b_out, out);
}